// Round 10
// baseline (192.170 us; speedup 1.0000x reference)
//
#include <hip/hip_runtime.h>
#include <hip/hip_bf16.h>

// ---------------------------------------------------------------------------
// GPT-2 attention block on MI355X (gfx950), bf16 MFMA compute.
//   qkv = x @ w_attn + b_attn ; split q,k,v ; causal softmax(q k^T / 8) v ;
//   out = attn @ w_proj + b_proj.  Outputs: out, k^T [B,H,D,S], v [B,H,S,D].
// Round 10: GEMM mainloop -> 2-phase double-buffered prefetch (attn-proven
// pattern, 1 barrier/K-step), grid order swapped so consecutive blocks share
// the small B weight-panel (L2-resident per XCD).
// ---------------------------------------------------------------------------

typedef __attribute__((ext_vector_type(8))) short bfx8;
typedef __attribute__((ext_vector_type(4))) short bfx4;
typedef __attribute__((ext_vector_type(4))) float fx4;

#define MFMA(a, b, c) __builtin_amdgcn_mfma_f32_16x16x32_bf16(a, b, c, 0, 0, 0)

#define S_CTX 2048
#define NE 1024
#define NH 16
#define HD 64

// Q pre-scale: (1/sqrt(64)) * log2(e) -> softmax runs in exp2 domain
#define QSCALE 0.18033688011112042f

__device__ __forceinline__ short f2bf(float f) {
  unsigned u = __float_as_uint(f);
  unsigned r = u + 0x7fffu + ((u >> 16) & 1u);  // round-to-nearest-even
  return (short)(r >> 16);
}

// pairwise f32 -> packed bf16x2 via the header (compiler-scheduled, no asm)
__device__ __forceinline__ unsigned pkbf(float a, float b) {
  union {
    __hip_bfloat162 h;
    unsigned u;
  } c;
  c.h = __float22bfloat162_rn(make_float2(a, b));
  return c.u;
}

__device__ __forceinline__ void gload16(const void* g, void* l) {
  __builtin_amdgcn_global_load_lds(
      (const __attribute__((address_space(1))) unsigned int*)g,
      (__attribute__((address_space(3))) unsigned int*)l, 16, 0, 0);
}

// ---------------- fp32 -> bf16 convert (vectorized) ------------------------
__global__ __launch_bounds__(256) void convert_bf16_kernel(const float* __restrict__ in,
                                                           short* __restrict__ out) {
  size_t i = (size_t)blockIdx.x * 256 + threadIdx.x;  // quad index
  fx4 v = *(const fx4*)(in + i * 4);
  bfx4 o;
#pragma unroll
  for (int j = 0; j < 4; ++j) o[j] = f2bf(v[j]);
  *(bfx4*)(out + i * 4) = o;
}

// ------------- fp32 [R][C] -> bf16 [C][R] transpose ------------------------
__global__ __launch_bounds__(256) void transpose_conv_kernel(const float* __restrict__ in,
                                                             short* __restrict__ out,
                                                             int R, int C) {
  __shared__ float tile[32][33];
  int tx = threadIdx.x, ty = threadIdx.y;
  int c0 = blockIdx.x * 32, r0 = blockIdx.y * 32;
#pragma unroll
  for (int i = 0; i < 4; ++i)
    tile[ty + i * 8][tx] = in[(size_t)(r0 + ty + i * 8) * C + c0 + tx];
  __syncthreads();
#pragma unroll
  for (int i = 0; i < 4; ++i)
    out[(size_t)(c0 + ty + i * 8) * R + r0 + tx] = f2bf(tile[tx][ty + i * 8]);
}

// ---------------- shared 128x128 bf16 GEMM mainloop (2-phase dbuf) ---------
// C[M,N] = A[M,K] @ B[N,K]^T ; 4 waves in 2x2, each wave 64x64 (4x4 mfma
// frags). BK=64, double-buffered: stage tile tt+1 into buf^1 (global_load_lds
// width 16, pre-swizzled source), compute tile tt from buf, ONE barrier per
// K-step (drains prefetch vmcnt + publishes buffer). LDS [2][128 rows][64
// cols] bf16 per operand (64 KB total), slot ^= row&7 swizzle (rule #21).
__device__ __forceinline__ void gemm128_mainloop(const short* __restrict__ A,
                                                 const short* __restrict__ B,
                                                 const int K, const int m0, const int n0,
                                                 short* As, short* Bs, fx4 acc[4][4]) {
  const int t = threadIdx.x;
  const int lane = t & 63, w = t >> 6;
  const int g = lane >> 4, li = lane & 15;
  const int wr = w >> 1, wc = w & 1;
  const int bsw = ((lane & 7) ^ (lane >> 3)) * 8;  // source col offset (elems)
  const int rowl = w * 8 + (lane >> 3);            // staging row within issue stripe

#define GSTAGE(k0s, buf)                                                   \
  {                                                                        \
    _Pragma("unroll") for (int i = 0; i < 4; ++i) {                        \
      const int row = i * 32 + rowl;                                       \
      gload16(A + (size_t)(m0 + row) * K + (k0s) + bsw,                    \
              (char*)As + (buf) * 16384 + i * 4096 + w * 1024);            \
      gload16(B + (size_t)(n0 + row) * K + (k0s) + bsw,                    \
              (char*)Bs + (buf) * 16384 + i * 4096 + w * 1024);            \
    }                                                                      \
  }

  GSTAGE(0, 0);
  __syncthreads();  // tile 0 resident

  const int nt = K >> 6;
  for (int tt = 0; tt < nt; ++tt) {
    const int cur = tt & 1;
    if (tt + 1 < nt) GSTAGE((tt + 1) * 64, cur ^ 1);  // prefetch next tile
    const char* Ab = (const char*)As + cur * 16384;
    const char* Bb = (const char*)Bs + cur * 16384;
#pragma unroll
    for (int ks = 0; ks < 2; ++ks) {
      bfx8 af[4], bf[4];
#pragma unroll
      for (int m = 0; m < 4; ++m) {
        const int R = wr * 64 + m * 16 + li;
        af[m] = *(const bfx8*)(Ab + R * 128 + (((ks * 4 + g) ^ (li & 7)) << 4));
      }
#pragma unroll
      for (int n = 0; n < 4; ++n) {
        const int R = wc * 64 + n * 16 + li;
        bf[n] = *(const bfx8*)(Bb + R * 128 + (((ks * 4 + g) ^ (li & 7)) << 4));
      }
#pragma unroll
      for (int m = 0; m < 4; ++m)
#pragma unroll
        for (int n = 0; n < 4; ++n)
          acc[m][n] = MFMA(af[m], bf[n], acc[m][n]);
    }
    __syncthreads();  // drains prefetch vmcnt + publishes buf cur^1
  }
#undef GSTAGE
}

// ---------------- QKV GEMM with routing epilogue ---------------------------
__global__ __launch_bounds__(256) void gemm_qkv_kernel(const short* __restrict__ X,
                                                       const short* __restrict__ WT,
                                                       const float* __restrict__ bias,
                                                       short* __restrict__ qbf,
                                                       short* __restrict__ kbf,
                                                       short* __restrict__ vT,
                                                       float* __restrict__ kT,
                                                       float* __restrict__ vout) {
  __shared__ short As[2 * 128 * 64];
  __shared__ short Bs[2 * 128 * 64];
  fx4 acc[4][4];
  const fx4 z = {0.f, 0.f, 0.f, 0.f};
#pragma unroll
  for (int m = 0; m < 4; ++m)
#pragma unroll
    for (int n = 0; n < 4; ++n) acc[m][n] = z;
  const int m0 = blockIdx.x * 128, n0 = blockIdx.y * 128;  // m fastest: share B-panel
  gemm128_mainloop(X, WT, 1024, m0, n0, As, Bs, acc);

  const int lane = threadIdx.x & 63, w = threadIdx.x >> 6;
  const int g = lane >> 4, li = lane & 15;
  const int wr = w >> 1, wc = w & 1;
  const int sec = n0 >> 10;  // whole 128-tile lies in one of q/k/v sections
#pragma unroll
  for (int mf = 0; mf < 4; ++mf) {
#pragma unroll
    for (int nf = 0; nf < 4; ++nf) {
      const int mrow = m0 + wr * 64 + mf * 16 + g * 4;  // + jj
      const int ncol = n0 + wc * 64 + nf * 16 + li;
      const float bv = bias[ncol];
      fx4 vv;
#pragma unroll
      for (int jj = 0; jj < 4; ++jj) vv[jj] = acc[mf][nf][jj] + bv;
      const int b = mrow >> 11, s = mrow & 2047;
      const int e = ncol & 1023, h = e >> 6, d = e & 63;
      const size_t bidx = ((size_t)((b * 16 + h) * 2048 + s)) * 64 + d;
      if (sec == 0) {
#pragma unroll
        for (int jj = 0; jj < 4; ++jj) qbf[bidx + (size_t)jj * 64] = f2bf(vv[jj] * QSCALE);
      } else if (sec == 1) {
#pragma unroll
        for (int jj = 0; jj < 4; ++jj) kbf[bidx + (size_t)jj * 64] = f2bf(vv[jj]);
        const size_t tb = ((size_t)((b * 16 + h) * 64 + d)) * 2048 + s;
        *(fx4*)(kT + tb) = vv;  // 4 consecutive s for fixed d
      } else {
#pragma unroll
        for (int jj = 0; jj < 4; ++jj) vout[bidx + (size_t)jj * 64] = vv[jj];
        const size_t tb = ((size_t)((b * 16 + h) * 64 + d)) * 2048 + s;
        bfx4 pv;
#pragma unroll
        for (int jj = 0; jj < 4; ++jj) pv[jj] = f2bf(vv[jj]);
        *(bfx4*)(vT + tb) = pv;
      }
    }
  }
}

// ---------------- output projection GEMM -----------------------------------
__global__ __launch_bounds__(256) void gemm_proj_kernel(const short* __restrict__ X,
                                                        const short* __restrict__ WT,
                                                        const float* __restrict__ bias,
                                                        float* __restrict__ out) {
  __shared__ short As[2 * 128 * 64];
  __shared__ short Bs[2 * 128 * 64];
  fx4 acc[4][4];
  const fx4 z = {0.f, 0.f, 0.f, 0.f};
#pragma unroll
  for (int m = 0; m < 4; ++m)
#pragma unroll
    for (int n = 0; n < 4; ++n) acc[m][n] = z;
  const int m0 = blockIdx.x * 128, n0 = blockIdx.y * 128;  // m fastest: share B-panel
  gemm128_mainloop(X, WT, 1024, m0, n0, As, Bs, acc);

  const int lane = threadIdx.x & 63, w = threadIdx.x >> 6;
  const int g = lane >> 4, li = lane & 15;
  const int wr = w >> 1, wc = w & 1;
#pragma unroll
  for (int mf = 0; mf < 4; ++mf) {
#pragma unroll
    for (int nf = 0; nf < 4; ++nf) {
      const int mrow = m0 + wr * 64 + mf * 16 + g * 4;
      const int ncol = n0 + wc * 64 + nf * 16 + li;
      const float bv = bias[ncol];
#pragma unroll
      for (int jj = 0; jj < 4; ++jj)
        out[(size_t)(mrow + jj) * 1024 + ncol] = acc[mf][nf][jj] + bv;
    }
  }
}

// ---------------- causal flash attention (balanced mirrored pairs) ---------
// Block: one head, chunk pair (c, 31-c) of 64 q-rows each. 4 waves; wave w
// owns m-frag mf0 = rows 64c+16w (low, active tiles tt<=c, wave-uniform) and
// mf1 = rows 64(31-c)+16w (high, active all tiles). Every block = 33 tile-
// units of compute -> uniform CU load, no causal tail.
// Swapped QK^T: S^T = mfma(K, Q) => lane holds q = lane&15, keys = g*4+jj.
// K tile [64 keys][64 d] and V^T tile [64 d][64 keys] in double-buffered LDS.
// Staging: global_load_lds width 16, LINEAR dest + pre-swizzled global src
// (bsw = ((lane&7)^(lane>>3))*16); reads use matching KSW XOR swizzle.
#define KSW(base, row, byte) ((char*)(base) + (row) * 128 + ((byte) ^ (((row) & 7) << 4)))

// per-tile softmax for one m-frag (exp2 domain, defer-max, pairwise pk cvt)
#define SOFTMAX_TILE(stv, accv, mrun, lrun, pAv, qm, diag)                    \
  {                                                                          \
    if (diag) {                                                              \
      const int qg = (qm) + li;                                              \
      _Pragma("unroll") for (int kt = 0; kt < 4; ++kt)                       \
          _Pragma("unroll") for (int jj = 0; jj < 4; ++jj) if (              \
              k0 + kt * 16 + g * 4 + jj > qg) stv[kt][jj] = -1e30f;          \
    }                                                                        \
    float pm = stv[0][0];                                                    \
    _Pragma("unroll") for (int kt = 0; kt < 4; ++kt)                         \
        _Pragma("unroll") for (int jj = 0; jj < 4; ++jj) pm =                \
            fmaxf(pm, stv[kt][jj]);                                          \
    if (!__all(pm <= (mrun) + 6.0f)) {                                       \
      pm = fmaxf(pm, __shfl_xor(pm, 16));                                    \
      pm = fmaxf(pm, __shfl_xor(pm, 32));                                    \
      const float mn = fmaxf((mrun), pm);                                    \
      const float rf = __builtin_amdgcn_exp2f((mrun) - mn);                  \
      (lrun) *= rf;                                                          \
      fx4 rfv;                                                               \
      _Pragma("unroll") for (int jj = 0; jj < 4; ++jj) rfv[jj] =             \
          __shfl(rf, g * 4 + jj);                                            \
      _Pragma("unroll") for (int dt = 0; dt < 4; ++dt) accv[dt] *= rfv;      \
      (mrun) = mn;                                                           \
    }                                                                        \
    union {                                                                  \
      bfx8 v;                                                                \
      unsigned u[4];                                                         \
    } pk_[2];                                                                \
    float ls = 0.f;                                                          \
    _Pragma("unroll") for (int kt = 0; kt < 4; ++kt) {                       \
      const float p0 = __builtin_amdgcn_exp2f(stv[kt][0] - (mrun));          \
      const float p1 = __builtin_amdgcn_exp2f(stv[kt][1] - (mrun));          \
      const float p2 = __builtin_amdgcn_exp2f(stv[kt][2] - (mrun));          \
      const float p3 = __builtin_amdgcn_exp2f(stv[kt][3] - (mrun));          \
      ls += (p0 + p1) + (p2 + p3);                                           \
      pk_[kt >> 1].u[(kt & 1) * 2 + 0] = pkbf(p0, p1);                       \
      pk_[kt >> 1].u[(kt & 1) * 2 + 1] = pkbf(p2, p3);                       \
    }                                                                        \
    ls += __shfl_xor(ls, 16);                                                \
    ls += __shfl_xor(ls, 32);                                                \
    (lrun) += ls;                                                            \
    pAv[0] = pk_[0].v;                                                       \
    pAv[1] = pk_[1].v;                                                       \
  }

__global__ __launch_bounds__(256, 4) void attn_kernel(const short* __restrict__ Q,
                                                      const short* __restrict__ Kc,
                                                      const short* __restrict__ VT,
                                                      short* __restrict__ O) {
  __shared__ short Ks[2][64 * 64];
  __shared__ short Vs[2][64 * 64];

  const int bh = blockIdx.x & 63;
  const int c = blockIdx.x >> 6;  // 0..15; heaviest span (c=0) dispatched first

  const int t = threadIdx.x;
  const int w = t >> 6;
  const int lane = t & 63;
  const int g = lane >> 4, li = lane & 15;

  const size_t hoff = (size_t)bh * (S_CTX * HD);
  const short* Qh = Q + hoff;
  const char* Khc = (const char*)(Kc + hoff);  // [S][64] rows of 128B
  const char* Vhc = (const char*)(VT + hoff);  // [64][S] rows of 4096B

  const int lr = lane >> 3;
  const int bsw = ((lane & 7) ^ lr) * 16;
  const int rb0 = w * 16;  // wave's 16-row staging stripe

  const int qm0 = 64 * c + 16 * w;         // low m-frag rows
  const int qm1 = 64 * (31 - c) + 16 * w;  // high m-frag rows
  bfx8 qf0[2], qf1[2];
  qf0[0] = *(const bfx8*)(Qh + (size_t)(qm0 + li) * HD + g * 8);
  qf0[1] = *(const bfx8*)(Qh + (size_t)(qm0 + li) * HD + 32 + g * 8);
  qf1[0] = *(const bfx8*)(Qh + (size_t)(qm1 + li) * HD + g * 8);
  qf1[1] = *(const bfx8*)(Qh + (size_t)(qm1 + li) * HD + 32 + g * 8);

  fx4 acc0[4], acc1[4];
  const fx4 z = {0.f, 0.f, 0.f, 0.f};
#pragma unroll
  for (int dt = 0; dt < 4; ++dt) {
    acc0[dt] = z;
    acc1[dt] = z;
  }
  float m0 = -1e30f, l0 = 0.f, m1 = -1e30f, l1 = 0.f;

  const int tmax = 31 - c;  // tiles tt=0..tmax, k0 = 64*tt

#define STAGE_TILE(k0s, buf)                                                        \
  {                                                                                 \
    _Pragma("unroll") for (int i = 0; i < 2; ++i) {                                 \
      const int rb = rb0 + i * 8;                                                   \
      const int row = rb + lr;                                                      \
      gload16(Khc + (size_t)((k0s) + row) * 128 + bsw, (char*)Ks[buf] + rb * 128);  \
      gload16(Vhc + (size_t)row * (S_CTX * 2) + (size_t)(k0s) * 2 + bsw,            \
              (char*)Vs[buf] + rb * 128);                                           \
    }                                                                               \
  }

  STAGE_TILE(0, 0);
  __syncthreads();  // drains vmcnt(0): tile 0 resident

  for (int tt = 0; tt <= tmax; ++tt) {
    const int cur = tt & 1;
    const int k0 = tt * 64;
    if (tt < tmax) STAGE_TILE(k0 + 64, cur ^ 1);  // prefetch, hides under compute
    const bool act0 = (tt <= c);                  // low frag active (wave-uniform)

    bfx8 pA0[2], pA1[2];
    {  // ---- high frag QK^T + softmax (always active) ----
      fx4 st[4] = {z, z, z, z};
#pragma unroll
      for (int h = 0; h < 2; ++h) {
        bfx8 kfh[4];
#pragma unroll
        for (int kt = 0; kt < 4; ++kt)
          kfh[kt] = *(const bfx8*)KSW(Ks[cur], kt * 16 + li, h * 64 + g * 16);
#pragma unroll
        for (int kt = 0; kt < 4; ++kt) st[kt] = MFMA(kfh[kt], qf1[h], st[kt]);
      }
      SOFTMAX_TILE(st, acc1, m1, l1, pA1, qm1, tt == tmax);
    }
    if (act0) {  // ---- low frag QK^T + softmax (st registers reused) ----
      fx4 st[4] = {z, z, z, z};
#pragma unroll
      for (int h = 0; h < 2; ++h) {
        bfx8 kfh[4];
#pragma unroll
        for (int kt = 0; kt < 4; ++kt)
          kfh[kt] = *(const bfx8*)KSW(Ks[cur], kt * 16 + li, h * 64 + g * 16);
#pragma unroll
        for (int kt = 0; kt < 4; ++kt) st[kt] = MFMA(kfh[kt], qf0[h], st[kt]);
      }
      SOFTMAX_TILE(st, acc0, m0, l0, pA0, qm0, tt == c);
    }
    // ---- PV (V-frags loaded per 32-key chunk, key-permuted, shared) ----
#pragma unroll
    for (int kc = 0; kc < 2; ++kc) {
      bfx8 vfc[4];
#pragma unroll
      for (int dt = 0; dt < 4; ++dt) {
        const int row = dt * 16 + li;
        const bfx4 a = *(const bfx4*)KSW(Vs[cur], row, kc * 64 + g * 8);
        const bfx4 b = *(const bfx4*)KSW(Vs[cur], row, kc * 64 + 32 + g * 8);
        bfx8 vv;
#pragma unroll
        for (int j = 0; j < 4; ++j) {
          vv[j] = a[j];
          vv[j + 4] = b[j];
        }
        vfc[dt] = vv;
      }
#pragma unroll
      for (int dt = 0; dt < 4; ++dt) acc1[dt] = MFMA(pA1[kc], vfc[dt], acc1[dt]);
      if (act0) {
#pragma unroll
        for (int dt = 0; dt < 4; ++dt) acc0[dt] = MFMA(pA0[kc], vfc[dt], acc0[dt]);
      }
    }
    __syncthreads();  // drains prefetch vmcnt + publishes buf cur^1
  }

  // ---- epilogue: divide by l, merge heads (both frags) ----
  const int b = bh >> 4, h = bh & 15;
#pragma unroll
  for (int mf = 0; mf < 2; ++mf) {
    const int qm = mf ? qm1 : qm0;
    const float lr_ = mf ? l1 : l0;
    fx4 lv;
#pragma unroll
    for (int jj = 0; jj < 4; ++jj)
      lv[jj] = __builtin_amdgcn_rcpf(__shfl(lr_, g * 4 + jj));
#pragma unroll
    for (int dt = 0; dt < 4; ++dt)
#pragma unroll
      for (int jj = 0; jj < 4; ++jj) {
        const int s = qm + g * 4 + jj;
        const fx4 av = mf ? acc1[dt] : acc0[dt];
        O[((size_t)(b * S_CTX + s)) * NE + h * HD + dt * 16 + li] =
            f2bf(av[jj] * lv[jj]);
      }
  }
}

// ---------------------------------------------------------------------------
extern "C" void kernel_launch(void* const* d_in, const int* in_sizes, int n_in,
                              void* d_out, int out_size, void* d_ws, size_t ws_size,
                              hipStream_t stream) {
  const float* hs = (const float*)d_in[0];      // [4,2048,1024]
  const float* w_attn = (const float*)d_in[1];  // [1024,3072]
  const float* b_attn = (const float*)d_in[2];  // [3072]
  const float* w_proj = (const float*)d_in[3];  // [1024,1024]
  const float* b_proj = (const float*)d_in[4];  // [1024]

  float* out = (float*)d_out;            // [4,2048,1024]
  float* kT_out = out + 8388608;         // [4,16,64,2048]
  float* v_out = out + 2 * 8388608;      // [4,16,2048,64]

  char* ws = (char*)d_ws;
  short* xbf = (short*)ws;                      // 16 MiB: x bf16, reused as attn out
  short* waT = (short*)(ws + 16777216);         //  6 MiB: w_attn^T bf16 [3072][1024]
  short* vTb = (short*)(ws + 23068672);         // 16 MiB: V^T bf16 [B,H,D,S]
  short* qbf = (short*)(ws + 39845888);         // 16 MiB: Q bf16 (pre-scaled QSCALE)
  short* kbf = (short*)(ws + 56623104);         // 16 MiB: K bf16
  short* wpT = (short*)(ws + 73400320);         //  2 MiB: w_proj^T bf16

  convert_bf16_kernel<<<8192, 256, 0, stream>>>(hs, xbf);
  transpose_conv_kernel<<<dim3(96, 32), dim3(32, 8), 0, stream>>>(w_attn, waT, 1024, 3072);
  transpose_conv_kernel<<<dim3(32, 32), dim3(32, 8), 0, stream>>>(w_proj, wpT, 1024, 1024);
  gemm_qkv_kernel<<<dim3(64, 24), 256, 0, stream>>>(xbf, waT, b_attn, qbf, kbf, vTb,
                                                    kT_out, v_out);
  attn_kernel<<<1024, 256, 0, stream>>>(qbf, kbf, vTb, xbf /* attn out */);
  gemm_proj_kernel<<<dim3(64, 8), 256, 0, stream>>>(xbf, wpT, b_proj, out);
}

// Round 12
// 176.109 us; speedup vs baseline: 1.0912x; 1.0912x over previous
//
#include <hip/hip_runtime.h>
#include <hip/hip_bf16.h>

// ---------------------------------------------------------------------------
// GPT-2 attention block on MI355X (gfx950), bf16 MFMA compute.
//   qkv = x @ w_attn + b_attn ; split q,k,v ; causal softmax(q k^T / 8) v ;
//   out = attn @ w_proj + b_proj.  Outputs: out, k^T [B,H,D,S], v [B,H,S,D].
// Round 12 (= Round 11 resubmit after infra failure): revert round-10 dbuf
// (64KB LDS halved occupancy, m132/m99 lesson). Single-buffered mainloop +
// m-fastest grid (kept: FETCH 72->49MB) + hoisted staging pointers.
// ---------------------------------------------------------------------------

typedef __attribute__((ext_vector_type(8))) short bfx8;
typedef __attribute__((ext_vector_type(4))) short bfx4;
typedef __attribute__((ext_vector_type(4))) float fx4;

#define MFMA(a, b, c) __builtin_amdgcn_mfma_f32_16x16x32_bf16(a, b, c, 0, 0, 0)

#define S_CTX 2048
#define NE 1024
#define NH 16
#define HD 64

// Q pre-scale: (1/sqrt(64)) * log2(e) -> softmax runs in exp2 domain
#define QSCALE 0.18033688011112042f

__device__ __forceinline__ short f2bf(float f) {
  unsigned u = __float_as_uint(f);
  unsigned r = u + 0x7fffu + ((u >> 16) & 1u);  // round-to-nearest-even
  return (short)(r >> 16);
}

// pairwise f32 -> packed bf16x2 via the header (compiler-scheduled, no asm)
__device__ __forceinline__ unsigned pkbf(float a, float b) {
  union {
    __hip_bfloat162 h;
    unsigned u;
  } c;
  c.h = __float22bfloat162_rn(make_float2(a, b));
  return c.u;
}

__device__ __forceinline__ void gload16(const void* g, void* l) {
  __builtin_amdgcn_global_load_lds(
      (const __attribute__((address_space(1))) unsigned int*)g,
      (__attribute__((address_space(3))) unsigned int*)l, 16, 0, 0);
}

// ---------------- fp32 -> bf16 convert (vectorized) ------------------------
__global__ __launch_bounds__(256) void convert_bf16_kernel(const float* __restrict__ in,
                                                           short* __restrict__ out) {
  size_t i = (size_t)blockIdx.x * 256 + threadIdx.x;  // quad index
  fx4 v = *(const fx4*)(in + i * 4);
  bfx4 o;
#pragma unroll
  for (int j = 0; j < 4; ++j) o[j] = f2bf(v[j]);
  *(bfx4*)(out + i * 4) = o;
}

// ------------- fp32 [R][C] -> bf16 [C][R] transpose ------------------------
__global__ __launch_bounds__(256) void transpose_conv_kernel(const float* __restrict__ in,
                                                             short* __restrict__ out,
                                                             int R, int C) {
  __shared__ float tile[32][33];
  int tx = threadIdx.x, ty = threadIdx.y;
  int c0 = blockIdx.x * 32, r0 = blockIdx.y * 32;
#pragma unroll
  for (int i = 0; i < 4; ++i)
    tile[ty + i * 8][tx] = in[(size_t)(r0 + ty + i * 8) * C + c0 + tx];
  __syncthreads();
#pragma unroll
  for (int i = 0; i < 4; ++i)
    out[(size_t)(c0 + ty + i * 8) * R + r0 + tx] = f2bf(tile[tx][ty + i * 8]);
}

// ---------------- shared 128x128 bf16 GEMM mainloop (gload_lds) ------------
// C[M,N] = A[M,K] @ B[N,K]^T ; 4 waves in 2x2, each wave 64x64 (4x4 mfma
// frags). BK=64, single-buffered (32KB LDS -> high occupancy; dbuf regressed,
// round-10). LDS tiles [128 rows][64 cols] bf16, slot ^= row&7 swizzle via
// pre-swizzled source (rule #21). Staging pointers hoisted out of the K-loop.
__device__ __forceinline__ void gemm128_mainloop(const short* __restrict__ A,
                                                 const short* __restrict__ B,
                                                 const int K, const int m0, const int n0,
                                                 short* As, short* Bs, fx4 acc[4][4]) {
  const int t = threadIdx.x;
  const int lane = t & 63, w = t >> 6;
  const int g = lane >> 4, li = lane & 15;
  const int wr = w >> 1, wc = w & 1;
  const int bsw = ((lane & 7) ^ (lane >> 3)) * 8;  // source col offset (elems)
  const int rowl = w * 8 + (lane >> 3);            // staging row within issue stripe

  // hoisted per-lane staging pointers (advance +64 elems per K-step)
  const short* ap[4];
  const short* bp[4];
  char* al[4];
  char* bl[4];
#pragma unroll
  for (int i = 0; i < 4; ++i) {
    const int row = i * 32 + rowl;
    ap[i] = A + (size_t)(m0 + row) * K + bsw;
    bp[i] = B + (size_t)(n0 + row) * K + bsw;
    al[i] = (char*)As + i * 4096 + w * 1024;
    bl[i] = (char*)Bs + i * 4096 + w * 1024;
  }

  const int nt = K >> 6;
  for (int tt = 0; tt < nt; ++tt) {
#pragma unroll
    for (int i = 0; i < 4; ++i) {
      gload16(ap[i], al[i]);
      gload16(bp[i], bl[i]);
      ap[i] += 64;
      bp[i] += 64;
    }
    __syncthreads();  // drains vmcnt: tile resident
#pragma unroll
    for (int ks = 0; ks < 2; ++ks) {
      bfx8 af[4], bf[4];
#pragma unroll
      for (int m = 0; m < 4; ++m) {
        const int R = wr * 64 + m * 16 + li;
        af[m] = *(const bfx8*)((const char*)As + R * 128 + (((ks * 4 + g) ^ (li & 7)) << 4));
      }
#pragma unroll
      for (int n = 0; n < 4; ++n) {
        const int R = wc * 64 + n * 16 + li;
        bf[n] = *(const bfx8*)((const char*)Bs + R * 128 + (((ks * 4 + g) ^ (li & 7)) << 4));
      }
#pragma unroll
      for (int m = 0; m < 4; ++m)
#pragma unroll
        for (int n = 0; n < 4; ++n)
          acc[m][n] = MFMA(af[m], bf[n], acc[m][n]);
    }
    __syncthreads();
  }
}

// ---------------- QKV GEMM with routing epilogue ---------------------------
__global__ __launch_bounds__(256) void gemm_qkv_kernel(const short* __restrict__ X,
                                                       const short* __restrict__ WT,
                                                       const float* __restrict__ bias,
                                                       short* __restrict__ qbf,
                                                       short* __restrict__ kbf,
                                                       short* __restrict__ vT,
                                                       float* __restrict__ kT,
                                                       float* __restrict__ vout) {
  __shared__ short As[128 * 64];
  __shared__ short Bs[128 * 64];
  fx4 acc[4][4];
  const fx4 z = {0.f, 0.f, 0.f, 0.f};
#pragma unroll
  for (int m = 0; m < 4; ++m)
#pragma unroll
    for (int n = 0; n < 4; ++n) acc[m][n] = z;
  const int m0 = blockIdx.x * 128, n0 = blockIdx.y * 128;  // m fastest: share B-panel
  gemm128_mainloop(X, WT, 1024, m0, n0, As, Bs, acc);

  const int lane = threadIdx.x & 63, w = threadIdx.x >> 6;
  const int g = lane >> 4, li = lane & 15;
  const int wr = w >> 1, wc = w & 1;
  const int sec = n0 >> 10;  // whole 128-tile lies in one of q/k/v sections
#pragma unroll
  for (int mf = 0; mf < 4; ++mf) {
#pragma unroll
    for (int nf = 0; nf < 4; ++nf) {
      const int mrow = m0 + wr * 64 + mf * 16 + g * 4;  // + jj
      const int ncol = n0 + wc * 64 + nf * 16 + li;
      const float bv = bias[ncol];
      fx4 vv;
#pragma unroll
      for (int jj = 0; jj < 4; ++jj) vv[jj] = acc[mf][nf][jj] + bv;
      const int b = mrow >> 11, s = mrow & 2047;
      const int e = ncol & 1023, h = e >> 6, d = e & 63;
      const size_t bidx = ((size_t)((b * 16 + h) * 2048 + s)) * 64 + d;
      if (sec == 0) {
#pragma unroll
        for (int jj = 0; jj < 4; ++jj) qbf[bidx + (size_t)jj * 64] = f2bf(vv[jj] * QSCALE);
      } else if (sec == 1) {
#pragma unroll
        for (int jj = 0; jj < 4; ++jj) kbf[bidx + (size_t)jj * 64] = f2bf(vv[jj]);
        const size_t tb = ((size_t)((b * 16 + h) * 64 + d)) * 2048 + s;
        *(fx4*)(kT + tb) = vv;  // 4 consecutive s for fixed d
      } else {
#pragma unroll
        for (int jj = 0; jj < 4; ++jj) vout[bidx + (size_t)jj * 64] = vv[jj];
        const size_t tb = ((size_t)((b * 16 + h) * 64 + d)) * 2048 + s;
        bfx4 pv;
#pragma unroll
        for (int jj = 0; jj < 4; ++jj) pv[jj] = f2bf(vv[jj]);
        *(bfx4*)(vT + tb) = pv;
      }
    }
  }
}

// ---------------- output projection GEMM -----------------------------------
__global__ __launch_bounds__(256) void gemm_proj_kernel(const short* __restrict__ X,
                                                        const short* __restrict__ WT,
                                                        const float* __restrict__ bias,
                                                        float* __restrict__ out) {
  __shared__ short As[128 * 64];
  __shared__ short Bs[128 * 64];
  fx4 acc[4][4];
  const fx4 z = {0.f, 0.f, 0.f, 0.f};
#pragma unroll
  for (int m = 0; m < 4; ++m)
#pragma unroll
    for (int n = 0; n < 4; ++n) acc[m][n] = z;
  const int m0 = blockIdx.x * 128, n0 = blockIdx.y * 128;  // m fastest: share B-panel
  gemm128_mainloop(X, WT, 1024, m0, n0, As, Bs, acc);

  const int lane = threadIdx.x & 63, w = threadIdx.x >> 6;
  const int g = lane >> 4, li = lane & 15;
  const int wr = w >> 1, wc = w & 1;
#pragma unroll
  for (int mf = 0; mf < 4; ++mf) {
#pragma unroll
    for (int nf = 0; nf < 4; ++nf) {
      const int mrow = m0 + wr * 64 + mf * 16 + g * 4;
      const int ncol = n0 + wc * 64 + nf * 16 + li;
      const float bv = bias[ncol];
#pragma unroll
      for (int jj = 0; jj < 4; ++jj)
        out[(size_t)(mrow + jj) * 1024 + ncol] = acc[mf][nf][jj] + bv;
    }
  }
}

// ---------------- causal flash attention (balanced mirrored pairs) ---------
// Block: one head, chunk pair (c, 31-c) of 64 q-rows each. 4 waves; wave w
// owns m-frag mf0 = rows 64c+16w (low, active tiles tt<=c, wave-uniform) and
// mf1 = rows 64(31-c)+16w (high, active all tiles). Every block = 33 tile-
// units of compute -> uniform CU load, no causal tail.
// Swapped QK^T: S^T = mfma(K, Q) => lane holds q = lane&15, keys = g*4+jj.
// K tile [64 keys][64 d] and V^T tile [64 d][64 keys] in double-buffered LDS.
// Staging: global_load_lds width 16, LINEAR dest + pre-swizzled global src
// (bsw = ((lane&7)^(lane>>3))*16); reads use matching KSW XOR swizzle.
#define KSW(base, row, byte) ((char*)(base) + (row) * 128 + ((byte) ^ (((row) & 7) << 4)))

// per-tile softmax for one m-frag (exp2 domain, defer-max, pairwise pk cvt)
#define SOFTMAX_TILE(stv, accv, mrun, lrun, pAv, qm, diag)                    \
  {                                                                          \
    if (diag) {                                                              \
      const int qg = (qm) + li;                                              \
      _Pragma("unroll") for (int kt = 0; kt < 4; ++kt)                       \
          _Pragma("unroll") for (int jj = 0; jj < 4; ++jj) if (              \
              k0 + kt * 16 + g * 4 + jj > qg) stv[kt][jj] = -1e30f;          \
    }                                                                        \
    float pm = stv[0][0];                                                    \
    _Pragma("unroll") for (int kt = 0; kt < 4; ++kt)                         \
        _Pragma("unroll") for (int jj = 0; jj < 4; ++jj) pm =                \
            fmaxf(pm, stv[kt][jj]);                                          \
    if (!__all(pm <= (mrun) + 6.0f)) {                                       \
      pm = fmaxf(pm, __shfl_xor(pm, 16));                                    \
      pm = fmaxf(pm, __shfl_xor(pm, 32));                                    \
      const float mn = fmaxf((mrun), pm);                                    \
      const float rf = __builtin_amdgcn_exp2f((mrun) - mn);                  \
      (lrun) *= rf;                                                          \
      fx4 rfv;                                                               \
      _Pragma("unroll") for (int jj = 0; jj < 4; ++jj) rfv[jj] =             \
          __shfl(rf, g * 4 + jj);                                            \
      _Pragma("unroll") for (int dt = 0; dt < 4; ++dt) accv[dt] *= rfv;      \
      (mrun) = mn;                                                           \
    }                                                                        \
    union {                                                                  \
      bfx8 v;                                                                \
      unsigned u[4];                                                         \
    } pk_[2];                                                                \
    float ls = 0.f;                                                          \
    _Pragma("unroll") for (int kt = 0; kt < 4; ++kt) {                       \
      const float p0 = __builtin_amdgcn_exp2f(stv[kt][0] - (mrun));          \
      const float p1 = __builtin_amdgcn_exp2f(stv[kt][1] - (mrun));          \
      const float p2 = __builtin_amdgcn_exp2f(stv[kt][2] - (mrun));          \
      const float p3 = __builtin_amdgcn_exp2f(stv[kt][3] - (mrun));          \
      ls += (p0 + p1) + (p2 + p3);                                           \
      pk_[kt >> 1].u[(kt & 1) * 2 + 0] = pkbf(p0, p1);                       \
      pk_[kt >> 1].u[(kt & 1) * 2 + 1] = pkbf(p2, p3);                       \
    }                                                                        \
    ls += __shfl_xor(ls, 16);                                                \
    ls += __shfl_xor(ls, 32);                                                \
    (lrun) += ls;                                                            \
    pAv[0] = pk_[0].v;                                                       \
    pAv[1] = pk_[1].v;                                                       \
  }

__global__ __launch_bounds__(256, 4) void attn_kernel(const short* __restrict__ Q,
                                                      const short* __restrict__ Kc,
                                                      const short* __restrict__ VT,
                                                      short* __restrict__ O) {
  __shared__ short Ks[2][64 * 64];
  __shared__ short Vs[2][64 * 64];

  const int bh = blockIdx.x & 63;
  const int c = blockIdx.x >> 6;  // 0..15; heaviest span (c=0) dispatched first

  const int t = threadIdx.x;
  const int w = t >> 6;
  const int lane = t & 63;
  const int g = lane >> 4, li = lane & 15;

  const size_t hoff = (size_t)bh * (S_CTX * HD);
  const short* Qh = Q + hoff;
  const char* Khc = (const char*)(Kc + hoff);  // [S][64] rows of 128B
  const char* Vhc = (const char*)(VT + hoff);  // [64][S] rows of 4096B

  const int lr = lane >> 3;
  const int bsw = ((lane & 7) ^ lr) * 16;
  const int rb0 = w * 16;  // wave's 16-row staging stripe

  const int qm0 = 64 * c + 16 * w;         // low m-frag rows
  const int qm1 = 64 * (31 - c) + 16 * w;  // high m-frag rows
  bfx8 qf0[2], qf1[2];
  qf0[0] = *(const bfx8*)(Qh + (size_t)(qm0 + li) * HD + g * 8);
  qf0[1] = *(const bfx8*)(Qh + (size_t)(qm0 + li) * HD + 32 + g * 8);
  qf1[0] = *(const bfx8*)(Qh + (size_t)(qm1 + li) * HD + g * 8);
  qf1[1] = *(const bfx8*)(Qh + (size_t)(qm1 + li) * HD + 32 + g * 8);

  fx4 acc0[4], acc1[4];
  const fx4 z = {0.f, 0.f, 0.f, 0.f};
#pragma unroll
  for (int dt = 0; dt < 4; ++dt) {
    acc0[dt] = z;
    acc1[dt] = z;
  }
  float m0 = -1e30f, l0 = 0.f, m1 = -1e30f, l1 = 0.f;

  const int tmax = 31 - c;  // tiles tt=0..tmax, k0 = 64*tt

#define STAGE_TILE(k0s, buf)                                                        \
  {                                                                                 \
    _Pragma("unroll") for (int i = 0; i < 2; ++i) {                                 \
      const int rb = rb0 + i * 8;                                                   \
      const int row = rb + lr;                                                      \
      gload16(Khc + (size_t)((k0s) + row) * 128 + bsw, (char*)Ks[buf] + rb * 128);  \
      gload16(Vhc + (size_t)row * (S_CTX * 2) + (size_t)(k0s) * 2 + bsw,            \
              (char*)Vs[buf] + rb * 128);                                           \
    }                                                                               \
  }

  STAGE_TILE(0, 0);
  __syncthreads();  // drains vmcnt(0): tile 0 resident

  for (int tt = 0; tt <= tmax; ++tt) {
    const int cur = tt & 1;
    const int k0 = tt * 64;
    if (tt < tmax) STAGE_TILE(k0 + 64, cur ^ 1);  // prefetch, hides under compute
    const bool act0 = (tt <= c);                  // low frag active (wave-uniform)

    bfx8 pA0[2], pA1[2];
    {  // ---- high frag QK^T + softmax (always active) ----
      fx4 st[4] = {z, z, z, z};
#pragma unroll
      for (int h = 0; h < 2; ++h) {
        bfx8 kfh[4];
#pragma unroll
        for (int kt = 0; kt < 4; ++kt)
          kfh[kt] = *(const bfx8*)KSW(Ks[cur], kt * 16 + li, h * 64 + g * 16);
#pragma unroll
        for (int kt = 0; kt < 4; ++kt) st[kt] = MFMA(kfh[kt], qf1[h], st[kt]);
      }
      SOFTMAX_TILE(st, acc1, m1, l1, pA1, qm1, tt == tmax);
    }
    if (act0) {  // ---- low frag QK^T + softmax (st registers reused) ----
      fx4 st[4] = {z, z, z, z};
#pragma unroll
      for (int h = 0; h < 2; ++h) {
        bfx8 kfh[4];
#pragma unroll
        for (int kt = 0; kt < 4; ++kt)
          kfh[kt] = *(const bfx8*)KSW(Ks[cur], kt * 16 + li, h * 64 + g * 16);
#pragma unroll
        for (int kt = 0; kt < 4; ++kt) st[kt] = MFMA(kfh[kt], qf0[h], st[kt]);
      }
      SOFTMAX_TILE(st, acc0, m0, l0, pA0, qm0, tt == c);
    }
    // ---- PV (V-frags loaded per 32-key chunk, key-permuted, shared) ----
#pragma unroll
    for (int kc = 0; kc < 2; ++kc) {
      bfx8 vfc[4];
#pragma unroll
      for (int dt = 0; dt < 4; ++dt) {
        const int row = dt * 16 + li;
        const bfx4 a = *(const bfx4*)KSW(Vs[cur], row, kc * 64 + g * 8);
        const bfx4 b = *(const bfx4*)KSW(Vs[cur], row, kc * 64 + 32 + g * 8);
        bfx8 vv;
#pragma unroll
        for (int j = 0; j < 4; ++j) {
          vv[j] = a[j];
          vv[j + 4] = b[j];
        }
        vfc[dt] = vv;
      }
#pragma unroll
      for (int dt = 0; dt < 4; ++dt) acc1[dt] = MFMA(pA1[kc], vfc[dt], acc1[dt]);
      if (act0) {
#pragma unroll
        for (int dt = 0; dt < 4; ++dt) acc0[dt] = MFMA(pA0[kc], vfc[dt], acc0[dt]);
      }
    }
    __syncthreads();  // drains prefetch vmcnt + publishes buf cur^1
  }

  // ---- epilogue: divide by l, merge heads (both frags) ----
  const int b = bh >> 4, h = bh & 15;
#pragma unroll
  for (int mf = 0; mf < 2; ++mf) {
    const int qm = mf ? qm1 : qm0;
    const float lr_ = mf ? l1 : l0;
    fx4 lv;
#pragma unroll
    for (int jj = 0; jj < 4; ++jj)
      lv[jj] = __builtin_amdgcn_rcpf(__shfl(lr_, g * 4 + jj));
#pragma unroll
    for (int dt = 0; dt < 4; ++dt)
#pragma unroll
      for (int jj = 0; jj < 4; ++jj) {
        const int s = qm + g * 4 + jj;
        const fx4 av = mf ? acc1[dt] : acc0[dt];
        O[((size_t)(b * S_CTX + s)) * NE + h * HD + dt * 16 + li] =
            f2bf(av[jj] * lv[jj]);
      }
  }
}

// ---------------------------------------------------------------------------
extern "C" void kernel_launch(void* const* d_in, const int* in_sizes, int n_in,
                              void* d_out, int out_size, void* d_ws, size_t ws_size,
                              hipStream_t stream) {
  const float* hs = (const float*)d_in[0];      // [4,2048,1024]
  const float* w_attn = (const float*)d_in[1];  // [1024,3072]
  const float* b_attn = (const float*)d_in[2];  // [3072]
  const float* w_proj = (const float*)d_in[3];  // [1024,1024]
  const float* b_proj = (const float*)d_in[4];  // [1024]

  float* out = (float*)d_out;            // [4,2048,1024]
  float* kT_out = out + 8388608;         // [4,16,64,2048]
  float* v_out = out + 2 * 8388608;      // [4,16,2048,64]

  char* ws = (char*)d_ws;
  short* xbf = (short*)ws;                      // 16 MiB: x bf16, reused as attn out
  short* waT = (short*)(ws + 16777216);         //  6 MiB: w_attn^T bf16 [3072][1024]
  short* vTb = (short*)(ws + 23068672);         // 16 MiB: V^T bf16 [B,H,D,S]
  short* qbf = (short*)(ws + 39845888);         // 16 MiB: Q bf16 (pre-scaled QSCALE)
  short* kbf = (short*)(ws + 56623104);         // 16 MiB: K bf16
  short* wpT = (short*)(ws + 73400320);         //  2 MiB: w_proj^T bf16

  convert_bf16_kernel<<<8192, 256, 0, stream>>>(hs, xbf);
  transpose_conv_kernel<<<dim3(96, 32), dim3(32, 8), 0, stream>>>(w_attn, waT, 1024, 3072);
  transpose_conv_kernel<<<dim3(32, 32), dim3(32, 8), 0, stream>>>(w_proj, wpT, 1024, 1024);
  gemm_qkv_kernel<<<dim3(64, 24), 256, 0, stream>>>(xbf, waT, b_attn, qbf, kbf, vTb,
                                                    kT_out, v_out);
  attn_kernel<<<1024, 256, 0, stream>>>(qbf, kbf, vTb, xbf /* attn out */);
  gemm_proj_kernel<<<dim3(64, 8), 256, 0, stream>>>(xbf, wpT, b_proj, out);
}